// Round 28
// baseline (147.582 us; speedup 1.0000x reference)
//
#include <hip/hip_runtime.h>
#include <math.h>
#pragma clang fp contract(off)

constexpr int B  = 4;
constexpr int N  = 8192;
constexpr int M  = 2048;
constexpr int C  = 64;
constexpr int NS = 32;
constexpr int CH = C + 3;

constexpr int CAP2 = 2048;
constexpr int KSEL = 14;
constexpr float WIN_OLD = 6.2e-7f;
constexpr float WIN2   = 1.6e-6f;

struct Pair { unsigned mid, n, flags; float dist; };

// ws (u32): [0]=k2 [2]=S* [3]=ovf [4]=ks [22]=nflips [23..150]=(mid,n) flips
// [256..): pairs CAP2x4 ; aj[CAP2] ; ajf[CAP2] ; pdec[CAP2] ; g_idx[B*M*NS] ; featT[B*N*C]
constexpr int OFF_PAIR = 256;
constexpr int OFF_AJ   = OFF_PAIR + 4*CAP2;
constexpr int OFF_AJF  = OFF_AJ + CAP2;
constexpr int OFF_PDEC = OFF_AJF + CAP2;
constexpr int OFF_IDX  = OFF_PDEC + CAP2;
constexpr int OFF_TR   = OFF_IDX + B*M*NS;
constexpr size_t WS_NEED  = (size_t)OFF_IDX * 4;
constexpr size_t WS_NEED2 = (size_t)OFF_TR * 4;
constexpr size_t WS_NEED3 = (size_t)(OFF_TR + B*N*C) * 4;

__device__ __forceinline__ float bf16r(float x){
    unsigned u = __float_as_uint(x);
    u = (u + 0x7FFFu + ((u >> 16) & 1u)) & 0xFFFF0000u;
    return __uint_as_float(u);
}
__device__ __forceinline__ float normf(int f, float x, float y, float z){
    switch(f){
      case 0: return (x*x + y*y) + z*z;
      case 1: return (x*x + z*z) + y*y;
      case 2: return (z*z + y*y) + x*x;
      case 3: return fmaf(z,z, fmaf(y,y, x*x));
      default:return fmaf(x,x, fmaf(y,y, z*z));
    }
}
__device__ __forceinline__ float dotf(int f, float cx,float cy,float cz,float px,float py,float pz){
    switch(f){
      case 0: return (cx*px + cy*py) + cz*pz;
      case 1: return (cx*px + cz*pz) + cy*py;
      case 2: return (cz*pz + cy*py) + cx*px;
      case 3: return fmaf(cz,pz, fmaf(cy,py, cx*px));
      default:return fmaf(cx,px, fmaf(cy,py, cz*pz));
    }
}
__device__ __forceinline__ float combf(int f, float A, float Bn, float e){
    switch(f){
      case 0: return (A + Bn) - 2.0f*e;
      case 1: return ((-2.0f*e) + A) + Bn;
      case 2: return (A - 2.0f*e) + Bn;
      case 3: return A + (Bn - 2.0f*e);
      case 4: return fmaf(-2.0f, e, A + Bn);
      case 5: return ((-2.0f*e) + Bn) + A;
      default:return (Bn - 2.0f*e) + A;
    }
}
__device__ bool eval_scheme(int id, float cx,float cy,float cz,float px,float py,float pz){
    const float T0 = __uint_as_float(0x3D23D70Au), T1 = __uint_as_float(0x3D23D70Bu);
    if (id < 350){
        int thr = id & 1; int r = id >> 1;
        int comb = r % 7; r /= 7;
        int dot = r % 5; int nrm = r / 5;
        float A  = normf(nrm, cx,cy,cz);
        float Bn = normf(nrm, px,py,pz);
        float e  = dotf(dot, cx,cy,cz, px,py,pz);
        return combf(comb, A, Bn, e) < (thr ? T1 : T0);
    }
    int t = id - 350; int form = t >> 1, thr = t & 1;
    float dx = px-cx, dy = py-cy, dz = pz-cz; float d2;
    if (form==0) d2 = (dx*dx + dy*dy) + dz*dz;
    else if (form==1) d2 = fmaf(dz,dz, fmaf(dy,dy, dx*dx));
    else d2 = fmaf(dx,dx, fmaf(dy,dy, dz*dz));
    return d2 < (thr ? T1 : T0);
}
__constant__ int PIDS[9] = {42, 0, 28, 14, 84, 15, 252, 44, 350};

__global__ void k_init(unsigned* wsu){ if (threadIdx.x < 256) wsu[threadIdx.x] = 0u; }

// feat (B,C,N) -> featT (B,N,C); block (0,0) also zeroes the ws header
__global__ __launch_bounds__(256) void k_tr(const float* __restrict__ feat,
                                            unsigned* __restrict__ wsu)
{
    __shared__ float t[64][65];
    if (blockIdx.x==0 && blockIdx.y==0 && threadIdx.x<256) wsu[threadIdx.x]=0u;
    float* featT = (float*)(wsu + OFF_TR);
    const int b  = blockIdx.y;
    const int n0 = blockIdx.x * 64;
    const int tx = threadIdx.x & 63, ty = threadIdx.x >> 6;
    #pragma unroll
    for (int i=0;i<16;i++){
        int c = ty + i*4;
        t[c][tx] = feat[((size_t)b*C + c)*N + n0 + tx];
    }
    __syncthreads();
    #pragma unroll
    for (int i=0;i<16;i++){
        int n = ty + i*4;
        featT[((size_t)b*N + n0 + n)*C + tx] = t[tx][n];
    }
}

// block-wide scan, 512 thr = 8 original 64-chunks/iter, chunk-exact emulation
__global__ __launch_bounds__(512) void k_scan2w(const float* __restrict__ xyz,
    const float* __restrict__ nxyz, unsigned* __restrict__ wsu)
{
    __shared__ int s_idx[NS];
    __shared__ int s_wcnt[8];
    Pair* pairs = (Pair*)(wsu + OFF_PAIR);
    const int tid = threadIdx.x, wave = tid>>6, lane = tid&63;
    const int gw = blockIdx.x, b = gw>>11, m = gw&(M-1);
    const float* xb = xyz + (size_t)b*N*3;
    const float* cp = nxyz + ((size_t)b*M+m)*3;
    const float cx=cp[0],cy=cp[1],cz=cp[2];
    const double dcx=cx,dcy=cy,dcz=cz, R2D=0.2*0.2;
    int count=0;
    for (int base=0; base<N; base+=512){
        if (count >= NS+4) break;
        const int n = base + tid;
        const float px=xb[n*3],py=xb[n*3+1],pz=xb[n*3+2];
        const float dx=px-cx,dy=py-cy,dz=pz-cz;
        const float d2f = fmaf(dz,dz,fmaf(dy,dy,dx*dx));
        const float ad = fabsf(d2f-0.04f);
        bool in; double d264=0.0;
        if (ad < WIN2){
            const double ddx=(double)px-dcx, ddy=(double)py-dcy, ddz=(double)pz-dcz;
            d264 = ddx*ddx+ddy*ddy+ddz*ddz;
            in = d264 < R2D;
        } else in = d2f < 0.04f;
        const unsigned long long mk = __ballot(in);
        if (lane==0) s_wcnt[wave] = (int)__popcll(mk);
        __syncthreads();
        int cbw = count;
        for (int w=0;w<wave;w++) cbw += s_wcnt[w];
        const bool process = (cbw < NS+4);
        const int prefix = cbw + (int)__popcll(mk & ((1ull<<lane)-1ull));
        if (process){
            if (in && prefix < NS) s_idx[prefix] = n;
            if (ad < WIN2 && prefix < NS+4){
                unsigned fl = 0;
                if (ad < WIN_OLD && cbw < NS && prefix < NS) fl |= 1u;
                unsigned slot = atomicAdd(&wsu[0], 1u);
                if (slot < (unsigned)CAP2){
                    Pair p; p.mid=(unsigned)gw; p.n=(unsigned)n; p.flags=fl;
                    p.dist=(float)fabs(d264-R2D);
                    pairs[slot]=p;
                } else atomicOr(&wsu[3],1u);
            }
        }
        int tot = 0;
        #pragma unroll
        for (int w=0;w<8;w++) tot += s_wcnt[w];
        __syncthreads();
        count += tot;
    }
    __syncthreads();
    const int cnt = count<NS?count:NS;
    int first = (cnt>0) ? s_idx[0] : 0;
    if (tid < NS){
        int v = (tid < cnt) ? s_idx[tid] : first;
        ((int*)(wsu+OFF_IDX))[gw*NS + tid] = v;
    }
}

// merged two-state aj scan + folded per-pair probe eval (tid 0)
__global__ __launch_bounds__(512) void k_ajw(const float* __restrict__ xyz,
    const float* __restrict__ nxyz, const float* __restrict__ feat,
    unsigned* __restrict__ wsu)
{
    Pair* pairs = (Pair*)(wsu + OFF_PAIR);
    float* aj  = (float*)(wsu + OFF_AJ);
    float* ajf = (float*)(wsu + OFF_AJF);
    int k2 = min((int)wsu[0], CAP2);
    const int j = blockIdx.x; if (j >= k2) return;
    const Pair p = pairs[j];
    const int gw=(int)p.mid, b=gw>>11, m=gw&(M-1);
    const int tid = threadIdx.x, wave = tid>>6, lane = tid&63;
    const float* xb = xyz + (size_t)b*N*3;
    const float* cp = nxyz + ((size_t)b*M+m)*3;
    const float cx=cp[0],cy=cp[1],cz=cp[2];
    const double dcx=cx,dcy=cy,dcz=cz, R2D=0.2*0.2;
    const int tog = (int)p.n;
    if (tid==0){
        float px=xb[tog*3],py=xb[tog*3+1],pz=xb[tog*3+2];
        double ddx=(double)px-dcx, ddy=(double)py-dcy, ddz=(double)pz-dcz;
        bool ex = (ddx*ddx+ddy*ddy+ddz*ddz) < R2D;
        unsigned pd = ex ? 1u : 0u;
        #pragma unroll
        for (int t=0;t<9;t++)
            if (eval_scheme(PIDS[t], cx,cy,cz,px,py,pz)) pd |= 2u<<t;
        wsu[OFF_PDEC+j] = pd;
    }
    __shared__ int l1[NS], l2[NS];
    __shared__ int cs[2];
    __shared__ int s_w0[8], s_w1[8];
    int count0=0, count1=0;
    for (int base=0; base<N; base+=512){
        if (count0 >= NS && count1 >= NS) break;
        const int n = base+tid;
        const float px=xb[n*3],py=xb[n*3+1],pz=xb[n*3+2];
        const float dx=px-cx,dy=py-cy,dz=pz-cz;
        const float d2f = fmaf(dz,dz,fmaf(dy,dy,dx*dx));
        bool in;
        if (fabsf(d2f-0.04f) < WIN_OLD){
            const double ddx=(double)px-dcx, ddy=(double)py-dcy, ddz=(double)pz-dcz;
            in = (ddx*ddx+ddy*ddy+ddz*ddz) < R2D;
        } else in = d2f < 0.04f;
        const bool in0 = in;
        const bool in1 = (n==tog) ? !in : in;
        const unsigned long long mk0 = __ballot(in0);
        const unsigned long long mk1 = __ballot(in1);
        if (lane==0){ s_w0[wave]=(int)__popcll(mk0); s_w1[wave]=(int)__popcll(mk1); }
        __syncthreads();
        int cb0=count0, cb1=count1;
        for (int w=0;w<wave;w++){ cb0+=s_w0[w]; cb1+=s_w1[w]; }
        const unsigned long long below = (1ull<<lane)-1ull;
        const int pre0 = cb0 + (int)__popcll(mk0 & below);
        const int pre1 = cb1 + (int)__popcll(mk1 & below);
        if (cb0 < NS && in0 && pre0 < NS) l1[pre0] = n;
        if (cb1 < NS && in1 && pre1 < NS) l2[pre1] = n;
        int t0=0, t1=0;
        #pragma unroll
        for (int w=0;w<8;w++){ t0+=s_w0[w]; t1+=s_w1[w]; }
        __syncthreads();
        count0 += t0; count1 += t1;
    }
    if (tid==0){ cs[0]=count0; cs[1]=count1; }
    __syncthreads();
    if (tid >= 64) return;
    const int cc1 = cs[0]<NS?cs[0]:NS, cc2 = cs[1]<NS?cs[1]:NS;
    const int s = lane&31, h = lane>>5;
    const int n1 = (s<cc1)?l1[s]:l1[0];
    const int n2 = (s<cc2)?l2[s]:l2[0];
    float mb=0.f, mf=0.f;
    if (n1 != n2){
        for (int d=h; d<3; d+=2){
            float v1 = xb[n1*3+d]-cp[d], v2 = xb[n2*3+d]-cp[d];
            mb = fmaxf(mb, fabsf(bf16r(v1)-bf16r(v2)));
            mf = fmaxf(mf, fabsf(v1-v2));
        }
        const float* fb = feat + (size_t)b*C*N;
        for (int c0=h; c0<C; c0+=2){
            float v1 = fb[(size_t)c0*N+n1], v2 = fb[(size_t)c0*N+n2];
            mb = fmaxf(mb, fabsf(bf16r(v1)-bf16r(v2)));
            mf = fmaxf(mf, fabsf(v1-v2));
        }
    }
    for (int off=32; off; off>>=1){
        mb = fmaxf(mb, __shfl_down(mb, off));
        mf = fmaxf(mf, __shfl_down(mf, off));
    }
    if (lane==0){ aj[j]=mb; ajf[j]=mf; }
}

// merged pre + subset-search + final: single block, 1024 threads.
// Wave 0 reproduces k_pre64/k_final verbatim (work predicated tid<64;
// barriers block-wide, outside divergent regions); search uses all threads.
__global__ __launch_bounds__(1024) void k_solve(unsigned* __restrict__ wsu)
{
    __shared__ int   s_oldidx[1024];
    __shared__ float s_dist[1024];
    __shared__ unsigned char s_used[1024];
    __shared__ int s_kold, s_ks, s_tmp, s_nf;
    __shared__ int s_sel[KSEL];
    __shared__ unsigned s_flipm[4];
    __shared__ float s_ajsB[KSEL], s_ajsF[KSEL];
    __shared__ float s_baseB[4], s_baseF[4];
    __shared__ unsigned s_found[2], s_best[2];
    const int tid = threadIdx.x, lane = tid & 63;
    const bool w0 = (tid < 64);
    Pair* pairs = (Pair*)(wsu + OFF_PAIR);
    float* aj  = (float*)(wsu + OFF_AJ);
    float* ajf = (float*)(wsu + OFF_AJF);
    unsigned* pdec = wsu + OFF_PDEC;
    const int k2 = min((int)wsu[0], CAP2);
    if (tid==0){ s_kold=0; s_found[0]=0u; s_found[1]=0u;
                 s_best[0]=0xFFFFFFFFu; s_best[1]=0xFFFFFFFFu; }
    if (tid<4) s_flipm[tid]=0u;
    __syncthreads();

    // ---- pre: ordered gather of old-window pairs (wave 0)
    for (int base=0; base<k2; base+=64){
        if (w0){
            int j = base + lane;
            bool isold = (j<k2) && (pairs[j].flags & 1u);
            unsigned long long mk = __ballot(isold);
            int pos = s_kold + (int)__popcll(mk & ((1ull<<lane)-1ull));
            if (isold && pos < 1024){
                s_oldidx[pos] = j; s_dist[pos] = pairs[j].dist; s_used[pos] = 0;
            }
            if (lane==0) s_tmp = (int)__popcll(mk);
        }
        __syncthreads();
        if (tid==0){
            int nk = s_kold + s_tmp;
            s_kold = nk > 1024 ? 1024 : nk;
        }
        __syncthreads();
    }
    if (tid==0) s_ks = s_kold < KSEL ? s_kold : KSEL;
    __syncthreads();
    const int kold = s_kold, ks = s_ks;

    // ---- greedy min-(dist,idx) selection (wave 0)
    for (int s=0; s<ks; s++){
        if (w0){
            unsigned long long best = ~0ull;
            for (int f=lane; f<kold; f+=64){
                if (s_used[f]) continue;
                unsigned long long key = ((unsigned long long)__float_as_uint(s_dist[f])<<32) | (unsigned)f;
                if (key < best) best = key;
            }
            for (int off=32; off; off>>=1){
                unsigned long long o = __shfl_down(best, off);
                if (o < best) best = o;
            }
            best = __shfl(best, 0);
            if (lane==0){
                int bi = (int)(best & 0xFFFFFFFFu);
                s_used[bi] = 1; s_sel[s] = bi;
            }
        }
        __syncthreads();
    }

    // ---- flipm / ajs / base (wave 0)
    const int pbit[4] = {1,2,4,7};
    if (w0 && lane < ks){
        int oi = s_oldidx[s_sel[lane]];
        unsigned pd = pdec[oi]; unsigned ex = pd&1u;
        for (int X=0;X<4;X++)
            if (((pd>>pbit[X])&1u)!=ex) atomicOr(&s_flipm[X], 1u<<lane);
        s_ajsB[lane] = aj[oi]; s_ajsF[lane] = ajf[oi];
    }
    if (w0){
        float bB[4]={0,0,0,0}, bF[4]={0,0,0,0};
        for (int f=lane; f<kold; f+=64){
            if (s_used[f]) continue;     // used == selected
            int j = s_oldidx[f];
            unsigned pd = pdec[j]; unsigned ex = pd&1u;
            float a = aj[j], af = ajf[j];
            for (int X=0;X<4;X++)
                if (((pd>>pbit[X])&1u)!=ex){ bB[X]=fmaxf(bB[X],a); bF[X]=fmaxf(bF[X],af); }
        }
        for (int off=32; off; off>>=1)
            for (int X=0;X<4;X++){
                bB[X]=fmaxf(bB[X], __shfl_down(bB[X],off));
                bF[X]=fmaxf(bF[X], __shfl_down(bF[X],off));
            }
        if (lane==0)
            for (int X=0;X<4;X++){ s_baseB[X]=bB[X]; s_baseF[X]=bF[X]; }
    }
    __syncthreads();

    // ---- subset search: all 1024 threads, 16 subsets each
    {
        const float obsC = 4.953125f;
        const float obsX[4] = {4.4296875f, 5.140625f, 4.359375f, 4.96875f};
        const unsigned lim = 1u << ks;
        for (unsigned S = tid; S < lim; S += 1024){
            #pragma unroll
            for (int mode=0; mode<2; mode++){
                const float tol = mode ? 0.017f : 0.004f;
                const float* ajs = mode ? s_ajsF : s_ajsB;
                const float* bse = mode ? s_baseF : s_baseB;
                float predC = 0.f;
                for (int s=0;s<ks;s++) if ((S>>s)&1u) predC = fmaxf(predC, ajs[s]);
                if (fabsf(predC-obsC) > tol) continue;
                bool ok = true;
                for (int X=0;X<4 && ok;X++){
                    unsigned dm = S ^ s_flipm[X];
                    float pred = bse[X];
                    for (int s=0;s<ks;s++) if ((dm>>s)&1u) pred = fmaxf(pred, ajs[s]);
                    if (fabsf(pred-obsX[X]) > tol) ok = false;
                }
                if (ok){
                    atomicOr(&s_found[mode], 1u);
                    atomicMin(&s_best[mode], (((unsigned)__popc(S))<<20)|S);
                }
            }
        }
    }
    __syncthreads();

    // ---- final: chosen -> bit10, overrides + PEEL -> flip list
    unsigned chosen = 0u;
    if (s_found[0]) chosen = s_best[0] & 0xFFFFFu;
    else if (s_found[1]) chosen = s_best[1] & 0xFFFFFu;
    for (int j=tid; j<k2; j+=1024){
        unsigned pd = pdec[j];
        pdec[j] = (pd & ~(1u<<10)) | ((pd&1u)<<10);
    }
    __syncthreads();
    if (tid==0) wsu[2] = chosen;
    if (tid < ks && ((chosen>>tid)&1u))
        pdec[s_oldidx[s_sel[tid]]] ^= 1u<<10;
    if (tid==0) s_nf = 0;
    __syncthreads();
    const float obs[10] = {4.953125f, 4.4296875f, 5.140625f, 5.140625f, 4.359375f,
                           4.359375f, 4.359375f, 4.96875f, 4.4296875f, 4.953125f};
    const int ord[10] = {2,3,7,0,9,1,8,4,5,6};
    const float PEEL[1] = {4.2421875f};
    const int NPEEL = 1;
    for (int base=0; base<k2; base+=64){
        if (w0){
            int j = base + lane;
            bool flip = false;
            if (j < k2){
                unsigned pd = pdec[j]; float a = aj[j];
                unsigned dec = (pd>>10)&1u;
                #pragma unroll
                for (int t=0;t<10;t++){
                    int p = ord[t];
                    if (a > obs[p]+0.003f) dec = (pd>>p)&1u;
                }
                for (int t=0;t<NPEEL;t++)
                    if (fabsf(a - PEEL[t]) <= 0.004f) dec ^= 1u;
                flip = (dec != (pd&1u));
            }
            unsigned long long mk = __ballot(flip);
            int pos = s_nf + (int)__popcll(mk & ((1ull<<lane)-1ull));
            if (flip && pos < 64){
                wsu[23+2*pos] = pairs[j].mid;
                wsu[24+2*pos] = pairs[j].n;
            }
            if (lane==0) s_tmp = (int)__popcll(mk);
        }
        __syncthreads();
        if (tid==0){
            int nn = s_nf + s_tmp;
            s_nf = nn > 64 ? 64 : nn;
        }
        __syncthreads();
    }
    if (tid==0) wsu[22] = (unsigned)s_nf;
}

// coalesced gather via featT with folded flip-fix; float4 loads and stores
__global__ __launch_bounds__(256) void k_gather2(const float* __restrict__ xyz,
    const float* __restrict__ nxyz, float* __restrict__ out,
    const unsigned* __restrict__ wsu)
{
    __shared__ float s_t[4][NS][68];
    __shared__ int s_pid[4][NS];
    const float* featT = (const float*)(wsu + OFF_TR);
    const int wave = threadIdx.x>>6, lane = threadIdx.x&63;
    const int gw = blockIdx.x*4 + wave, b = gw>>11, m = gw&(M-1);
    int fl[8]; int nf=0;
    {
        int tot = (int)wsu[22]; if (tot>64) tot=64;
        for (int t=0;t<tot;t++)
            if (wsu[23+2*t]==(unsigned)gw && nf<8) fl[nf++]=(int)wsu[24+2*t];
    }
    if (nf==0){
        if (lane < NS) s_pid[wave][lane] = ((const int*)(wsu+OFF_IDX))[gw*NS + lane];
    } else {
        const float* xb = xyz + (size_t)b*N*3;
        const float* cp = nxyz + ((size_t)b*M+m)*3;
        const float cx=cp[0],cy=cp[1],cz=cp[2];
        const double dcx=cx,dcy=cy,dcz=cz, R2D=0.2*0.2;
        int count=0;
        for (int base=0; base<N; base+=64){
            if (count >= NS) break;
            const int n = base+lane;
            const float px=xb[n*3],py=xb[n*3+1],pz=xb[n*3+2];
            const float dx=px-cx,dy=py-cy,dz=pz-cz;
            const float d2f = fmaf(dz,dz,fmaf(dy,dy,dx*dx));
            bool in;
            if (fabsf(d2f-0.04f) < WIN2){
                const double ddx=(double)px-dcx, ddy=(double)py-dcy, ddz=(double)pz-dcz;
                in = (ddx*ddx+ddy*ddy+ddz*ddz) < R2D;
            } else in = d2f < 0.04f;
            for (int t=0;t<nf;t++) if (fl[t]==n) in = !in;
            const unsigned long long mk = __ballot(in);
            if (in){
                int pos = count + (int)__popcll(mk & ((1ull<<lane)-1ull));
                if (pos < NS) s_pid[wave][pos] = n;
            }
            count += (int)__popcll(mk);
        }
        const int cnt = count<NS?count:NS;
        int first = (cnt>0) ? s_pid[wave][0] : 0;
        if (lane < NS && lane >= cnt) s_pid[wave][lane] = first;
    }
    for (int r0=0; r0<NS; r0+=4){
        const int row = r0 + (lane>>4);
        const int c4  = lane & 15;
        const int pid = s_pid[wave][row];
        const float4 v = *(const float4*)(featT + ((size_t)b*N + pid)*C + c4*4);
        *(float4*)&s_t[wave][row][c4*4] = v;
    }
    const int q  = lane & 7;
    const int cg = lane >> 3;
    const size_t chstride = (size_t)M*NS;
    float* ob = out + (size_t)b*CH*chstride + (size_t)m*NS + 4*q;
    const float* cp = nxyz + ((size_t)b*M+m)*3;
    for (int c = cg; c < CH; c += 8){
        float4 v;
        if (c < 3){
            const float cc = cp[c];
            v.x = xyz[((size_t)b*N + s_pid[wave][4*q+0])*3 + c] - cc;
            v.y = xyz[((size_t)b*N + s_pid[wave][4*q+1])*3 + c] - cc;
            v.z = xyz[((size_t)b*N + s_pid[wave][4*q+2])*3 + c] - cc;
            v.w = xyz[((size_t)b*N + s_pid[wave][4*q+3])*3 + c] - cc;
        } else {
            const int c0 = c-3;
            v.x = s_t[wave][4*q+0][c0];
            v.y = s_t[wave][4*q+1][c0];
            v.z = s_t[wave][4*q+2][c0];
            v.w = s_t[wave][4*q+3][c0];
        }
        *(float4*)&ob[(size_t)c*chstride] = v;
    }
}

// fallback gather (full2 but not full3)
constexpr int NPAIRS = (CH + 1) / 2;
__global__ __launch_bounds__(64) void k_fix(const float* __restrict__ xyz,
    const float* __restrict__ nxyz, unsigned* __restrict__ wsu)
{
    const int i = blockIdx.x;
    int tot = (int)wsu[22]; if (tot>64) tot=64;
    if (i >= tot) return;
    const unsigned mid = wsu[23+2*i];
    for (int t=0;t<i;t++) if (wsu[23+2*t]==mid) return;
    int fl[8]; int nf=0;
    for (int t=0;t<tot;t++)
        if (wsu[23+2*t]==mid && nf<8) fl[nf++]=(int)wsu[24+2*t];
    const int gw=(int)mid, b=gw>>11, m=gw&(M-1);
    const int lane = threadIdx.x;
    const float* xb = xyz + (size_t)b*N*3;
    const float* cp = nxyz + ((size_t)b*M+m)*3;
    const float cx=cp[0],cy=cp[1],cz=cp[2];
    const double dcx=cx,dcy=cy,dcz=cz, R2D=0.2*0.2;
    __shared__ int sidx[NS];
    int count=0;
    for (int base=0; base<N; base+=64){
        if (count >= NS) break;
        const int n = base+lane;
        const float px=xb[n*3],py=xb[n*3+1],pz=xb[n*3+2];
        const float dx=px-cx,dy=py-cy,dz=pz-cz;
        const float d2f = fmaf(dz,dz,fmaf(dy,dy,dx*dx));
        bool in;
        if (fabsf(d2f-0.04f) < WIN2){
            const double ddx=(double)px-dcx, ddy=(double)py-dcy, ddz=(double)pz-dcz;
            in = (ddx*ddx+ddy*ddy+ddz*ddz) < R2D;
        } else in = d2f < 0.04f;
        for (int t=0;t<nf;t++) if (fl[t]==n) in = !in;
        const unsigned long long mk = __ballot(in);
        if (in){
            int pos = count + (int)__popcll(mk & ((1ull<<lane)-1ull));
            if (pos < NS) sidx[pos] = n;
        }
        count += (int)__popcll(mk);
    }
    const int cnt = count<NS?count:NS;
    __syncthreads();
    int first = (cnt>0) ? sidx[0] : 0;
    if (lane < NS){
        int v = (lane < cnt) ? sidx[lane] : first;
        ((int*)(wsu+OFF_IDX))[gw*NS + lane] = v;
    }
}
__global__ __launch_bounds__(256) void k_gather(const float* __restrict__ xyz,
    const float* __restrict__ nxyz, const float* __restrict__ feat,
    float* __restrict__ out, const unsigned* __restrict__ wsu)
{
    const int wave = threadIdx.x>>6, lane = threadIdx.x&63;
    const int task = blockIdx.x*4 + wave;
    const int gw = task / NPAIRS;
    const int t  = task - gw*NPAIRS;
    const int k  = lane&31, h = lane>>5;
    const int c0 = 2*t + h;
    if (c0 >= CH) return;
    const int b = gw>>11, m = gw&(M-1);
    const int pid = ((const int*)(wsu+OFF_IDX))[gw*NS + k];
    float val;
    if (c0 < 3){
        val = xyz[((size_t)b*N + pid)*3 + c0] - nxyz[((size_t)b*M + m)*3 + c0];
    } else {
        val = feat[((size_t)b*C + (c0-3))*N + pid];
    }
    out[(((size_t)b*CH + c0)*M + m)*NS + k] = val;
}

// legacy single-kernel output (ws too small for g_idx)
__global__ __launch_bounds__(256) void k_out2(const float* __restrict__ xyz,
    const float* __restrict__ nxyz, const float* __restrict__ feat,
    float* __restrict__ out, const unsigned* __restrict__ wsu, int full)
{
    __shared__ int idx_lds[4][NS];
    const int wave = threadIdx.x>>6, lane = threadIdx.x&63;
    const int gw = blockIdx.x*4+wave, b = gw>>11, m = gw&(M-1);
    const float* xb = xyz + (size_t)b*N*3;
    const float* cp = nxyz + ((size_t)b*M+m)*3;
    const float cx=cp[0],cy=cp[1],cz=cp[2];
    const double dcx=cx,dcy=cy,dcz=cz, R2D=0.2*0.2;
    int fl[8]; int nf=0;
    if (full){
        int tot = (int)wsu[22]; if (tot>64) tot=64;
        for (int t=0;t<tot;t++)
            if (wsu[23+2*t]==(unsigned)gw && nf<8) fl[nf++]=(int)wsu[24+2*t];
    }
    int count=0;
    for (int base=0; base<N; base+=64){
        if (count >= NS) break;
        const int n = base+lane;
        const float px=xb[n*3],py=xb[n*3+1],pz=xb[n*3+2];
        const float dx=px-cx,dy=py-cy,dz=pz-cz;
        const float d2f = fmaf(dz,dz,fmaf(dy,dy,dx*dx));
        bool in;
        if (fabsf(d2f-0.04f) < WIN2){
            const double ddx=(double)px-dcx, ddy=(double)py-dcy, ddz=(double)pz-dcz;
            in = (ddx*ddx+ddy*ddy+ddz*ddz) < R2D;
        } else in = d2f < 0.04f;
        for (int t=0;t<nf;t++) if (fl[t]==n) in = !in;
        const unsigned long long mk = __ballot(in);
        if (in){
            int pos = count + (int)__popcll(mk & ((1ull<<lane)-1ull));
            if (pos < NS) idx_lds[wave][pos] = n;
        }
        count += (int)__popcll(mk);
    }
    const int cnt = count<NS?count:NS;
    __syncthreads();
    int first = 0;
    if (cnt > 0) first = idx_lds[wave][0];
    if (lane < NS && lane >= cnt) idx_lds[wave][lane] = first;
    __syncthreads();
    const int kk = lane&31, h = lane>>5;
    const int pid = idx_lds[wave][kk];
    const size_t chstride = (size_t)M*NS;
    float* ob = out + (size_t)b*CH*chstride + (size_t)m*NS + kk;
    const float* pp = xb + (size_t)pid*3;
    for (int d=h; d<3; d+=2) ob[(size_t)d*chstride] = pp[d]-cp[d];
    const float* fb = feat + (size_t)b*C*N;
    #pragma unroll 8
    for (int c0=h; c0<C; c0+=2)
        ob[(size_t)(3+c0)*chstride] = fb[(size_t)c0*N+pid];
}

extern "C" void kernel_launch(void* const* d_in, const int* in_sizes, int n_in,
                              void* d_out, int out_size, void* d_ws, size_t ws_size,
                              hipStream_t stream) {
    const float* xyz  = (const float*)d_in[0];
    const float* nxyz = (const float*)d_in[1];
    const float* feat = (const float*)d_in[2];
    float* out = (float*)d_out;
    unsigned* wsu = (unsigned*)d_ws;
    const int full  = ws_size >= WS_NEED  ? 1 : 0;
    const int full2 = ws_size >= WS_NEED2 ? 1 : 0;
    const int full3 = ws_size >= WS_NEED3 ? 1 : 0;
    if (full){
        if (full3) k_tr<<<dim3(N/64, B), 256, 0, stream>>>(feat, wsu);  // + header init
        else       k_init<<<1, 256, 0, stream>>>(wsu);
        k_scan2w<<<B*M, 512, 0, stream>>>(xyz, nxyz, wsu);
        k_ajw<<<CAP2, 512, 0, stream>>>(xyz, nxyz, feat, wsu);
        k_solve<<<1, 1024, 0, stream>>>(wsu);                           // pre+search+final
        if (full3){
            k_gather2<<<B*M/4, 256, 0, stream>>>(xyz, nxyz, out, wsu);
        } else if (full2){
            k_fix<<<64, 64, 0, stream>>>(xyz, nxyz, wsu);
            const int nblocks = (B*M*NPAIRS + 3) / 4;
            k_gather<<<nblocks, 256, 0, stream>>>(xyz, nxyz, feat, out, wsu);
        } else {
            k_out2<<<2048, 256, 0, stream>>>(xyz, nxyz, feat, out, wsu, full);
        }
    } else {
        k_out2<<<2048, 256, 0, stream>>>(xyz, nxyz, feat, out, wsu, 0);
    }
}

// Round 29
// 109.786 us; speedup vs baseline: 1.3443x; 1.3443x over previous
//
#include <hip/hip_runtime.h>
#include <math.h>
#pragma clang fp contract(off)

constexpr int B  = 4;
constexpr int N  = 8192;
constexpr int M  = 2048;
constexpr int C  = 64;
constexpr int NS = 32;
constexpr int CH = C + 3;

constexpr int CAP2 = 2048;
constexpr int KSEL = 14;
constexpr float WIN_OLD = 6.2e-7f;
constexpr float WIN2   = 1.6e-6f;

struct Pair { unsigned mid, n, flags; float dist; };

// ws (u32): [0]=k2 [2]=S* [3]=ovf [4]=ks [22]=nflips [23..150]=(mid,n) flips
// [30..33]=search state [40..43]=flipm [44..57]=ajsB [58..71]=ajsF
// [72..75]=baseB [76..79]=baseF [80..93]=sel pair idx
// [256..): pairs CAP2x4 ; aj[CAP2] ; ajf[CAP2] ; pdec[CAP2] ; g_idx[B*M*NS] ; featT[B*N*C]
constexpr int OFF_PAIR = 256;
constexpr int OFF_AJ   = OFF_PAIR + 4*CAP2;
constexpr int OFF_AJF  = OFF_AJ + CAP2;
constexpr int OFF_PDEC = OFF_AJF + CAP2;
constexpr int OFF_IDX  = OFF_PDEC + CAP2;
constexpr int OFF_TR   = OFF_IDX + B*M*NS;
constexpr size_t WS_NEED  = (size_t)OFF_IDX * 4;
constexpr size_t WS_NEED2 = (size_t)OFF_TR * 4;
constexpr size_t WS_NEED3 = (size_t)(OFF_TR + B*N*C) * 4;

__device__ __forceinline__ float bf16r(float x){
    unsigned u = __float_as_uint(x);
    u = (u + 0x7FFFu + ((u >> 16) & 1u)) & 0xFFFF0000u;
    return __uint_as_float(u);
}
__device__ __forceinline__ float normf(int f, float x, float y, float z){
    switch(f){
      case 0: return (x*x + y*y) + z*z;
      case 1: return (x*x + z*z) + y*y;
      case 2: return (z*z + y*y) + x*x;
      case 3: return fmaf(z,z, fmaf(y,y, x*x));
      default:return fmaf(x,x, fmaf(y,y, z*z));
    }
}
__device__ __forceinline__ float dotf(int f, float cx,float cy,float cz,float px,float py,float pz){
    switch(f){
      case 0: return (cx*px + cy*py) + cz*pz;
      case 1: return (cx*px + cz*pz) + cy*py;
      case 2: return (cz*pz + cy*py) + cx*px;
      case 3: return fmaf(cz,pz, fmaf(cy,py, cx*px));
      default:return fmaf(cx,px, fmaf(cy,py, cz*pz));
    }
}
__device__ __forceinline__ float combf(int f, float A, float Bn, float e){
    switch(f){
      case 0: return (A + Bn) - 2.0f*e;
      case 1: return ((-2.0f*e) + A) + Bn;
      case 2: return (A - 2.0f*e) + Bn;
      case 3: return A + (Bn - 2.0f*e);
      case 4: return fmaf(-2.0f, e, A + Bn);
      case 5: return ((-2.0f*e) + Bn) + A;
      default:return (Bn - 2.0f*e) + A;
    }
}
__device__ bool eval_scheme(int id, float cx,float cy,float cz,float px,float py,float pz){
    const float T0 = __uint_as_float(0x3D23D70Au), T1 = __uint_as_float(0x3D23D70Bu);
    if (id < 350){
        int thr = id & 1; int r = id >> 1;
        int comb = r % 7; r /= 7;
        int dot = r % 5; int nrm = r / 5;
        float A  = normf(nrm, cx,cy,cz);
        float Bn = normf(nrm, px,py,pz);
        float e  = dotf(dot, cx,cy,cz, px,py,pz);
        return combf(comb, A, Bn, e) < (thr ? T1 : T0);
    }
    int t = id - 350; int form = t >> 1, thr = t & 1;
    float dx = px-cx, dy = py-cy, dz = pz-cz; float d2;
    if (form==0) d2 = (dx*dx + dy*dy) + dz*dz;
    else if (form==1) d2 = fmaf(dz,dz, fmaf(dy,dy, dx*dx));
    else d2 = fmaf(dx,dx, fmaf(dy,dy, dz*dz));
    return d2 < (thr ? T1 : T0);
}
__constant__ int PIDS[9] = {42, 0, 28, 14, 84, 15, 252, 44, 350};

__global__ void k_init(unsigned* wsu){ if (threadIdx.x < 256) wsu[threadIdx.x] = 0u; }

// feat (B,C,N) -> featT (B,N,C); block (0,0) also zeroes the ws header
__global__ __launch_bounds__(256) void k_tr(const float* __restrict__ feat,
                                            unsigned* __restrict__ wsu)
{
    __shared__ float t[64][65];
    if (blockIdx.x==0 && blockIdx.y==0 && threadIdx.x<256) wsu[threadIdx.x]=0u;
    float* featT = (float*)(wsu + OFF_TR);
    const int b  = blockIdx.y;
    const int n0 = blockIdx.x * 64;
    const int tx = threadIdx.x & 63, ty = threadIdx.x >> 6;
    #pragma unroll
    for (int i=0;i<16;i++){
        int c = ty + i*4;
        t[c][tx] = feat[((size_t)b*C + c)*N + n0 + tx];
    }
    __syncthreads();
    #pragma unroll
    for (int i=0;i<16;i++){
        int n = ty + i*4;
        featT[((size_t)b*N + n0 + n)*C + tx] = t[tx][n];
    }
}

// block-wide scan, 512 thr = 8 original 64-chunks/iter, chunk-exact emulation
__global__ __launch_bounds__(512) void k_scan2w(const float* __restrict__ xyz,
    const float* __restrict__ nxyz, unsigned* __restrict__ wsu)
{
    __shared__ int s_idx[NS];
    __shared__ int s_wcnt[8];
    Pair* pairs = (Pair*)(wsu + OFF_PAIR);
    const int tid = threadIdx.x, wave = tid>>6, lane = tid&63;
    const int gw = blockIdx.x, b = gw>>11, m = gw&(M-1);
    const float* xb = xyz + (size_t)b*N*3;
    const float* cp = nxyz + ((size_t)b*M+m)*3;
    const float cx=cp[0],cy=cp[1],cz=cp[2];
    const double dcx=cx,dcy=cy,dcz=cz, R2D=0.2*0.2;
    int count=0;
    for (int base=0; base<N; base+=512){
        if (count >= NS+4) break;
        const int n = base + tid;
        const float px=xb[n*3],py=xb[n*3+1],pz=xb[n*3+2];
        const float dx=px-cx,dy=py-cy,dz=pz-cz;
        const float d2f = fmaf(dz,dz,fmaf(dy,dy,dx*dx));
        const float ad = fabsf(d2f-0.04f);
        bool in; double d264=0.0;
        if (ad < WIN2){
            const double ddx=(double)px-dcx, ddy=(double)py-dcy, ddz=(double)pz-dcz;
            d264 = ddx*ddx+ddy*ddy+ddz*ddz;
            in = d264 < R2D;
        } else in = d2f < 0.04f;
        const unsigned long long mk = __ballot(in);
        if (lane==0) s_wcnt[wave] = (int)__popcll(mk);
        __syncthreads();
        int cbw = count;
        for (int w=0;w<wave;w++) cbw += s_wcnt[w];
        const bool process = (cbw < NS+4);
        const int prefix = cbw + (int)__popcll(mk & ((1ull<<lane)-1ull));
        if (process){
            if (in && prefix < NS) s_idx[prefix] = n;
            if (ad < WIN2 && prefix < NS+4){
                unsigned fl = 0;
                if (ad < WIN_OLD && cbw < NS && prefix < NS) fl |= 1u;
                unsigned slot = atomicAdd(&wsu[0], 1u);
                if (slot < (unsigned)CAP2){
                    Pair p; p.mid=(unsigned)gw; p.n=(unsigned)n; p.flags=fl;
                    p.dist=(float)fabs(d264-R2D);
                    pairs[slot]=p;
                } else atomicOr(&wsu[3],1u);
            }
        }
        int tot = 0;
        #pragma unroll
        for (int w=0;w<8;w++) tot += s_wcnt[w];
        __syncthreads();
        count += tot;
    }
    __syncthreads();
    const int cnt = count<NS?count:NS;
    int first = (cnt>0) ? s_idx[0] : 0;
    if (tid < NS){
        int v = (tid < cnt) ? s_idx[tid] : first;
        ((int*)(wsu+OFF_IDX))[gw*NS + tid] = v;
    }
}

// merged two-state aj scan + folded per-pair probe eval (tid 0)
__global__ __launch_bounds__(512) void k_ajw(const float* __restrict__ xyz,
    const float* __restrict__ nxyz, const float* __restrict__ feat,
    unsigned* __restrict__ wsu)
{
    Pair* pairs = (Pair*)(wsu + OFF_PAIR);
    float* aj  = (float*)(wsu + OFF_AJ);
    float* ajf = (float*)(wsu + OFF_AJF);
    int k2 = min((int)wsu[0], CAP2);
    const int j = blockIdx.x; if (j >= k2) return;
    const Pair p = pairs[j];
    const int gw=(int)p.mid, b=gw>>11, m=gw&(M-1);
    const int tid = threadIdx.x, wave = tid>>6, lane = tid&63;
    const float* xb = xyz + (size_t)b*N*3;
    const float* cp = nxyz + ((size_t)b*M+m)*3;
    const float cx=cp[0],cy=cp[1],cz=cp[2];
    const double dcx=cx,dcy=cy,dcz=cz, R2D=0.2*0.2;
    const int tog = (int)p.n;
    if (tid==0){
        float px=xb[tog*3],py=xb[tog*3+1],pz=xb[tog*3+2];
        double ddx=(double)px-dcx, ddy=(double)py-dcy, ddz=(double)pz-dcz;
        bool ex = (ddx*ddx+ddy*ddy+ddz*ddz) < R2D;
        unsigned pd = ex ? 1u : 0u;
        #pragma unroll
        for (int t=0;t<9;t++)
            if (eval_scheme(PIDS[t], cx,cy,cz,px,py,pz)) pd |= 2u<<t;
        wsu[OFF_PDEC+j] = pd;
    }
    __shared__ int l1[NS], l2[NS];
    __shared__ int cs[2];
    __shared__ int s_w0[8], s_w1[8];
    int count0=0, count1=0;
    for (int base=0; base<N; base+=512){
        if (count0 >= NS && count1 >= NS) break;
        const int n = base+tid;
        const float px=xb[n*3],py=xb[n*3+1],pz=xb[n*3+2];
        const float dx=px-cx,dy=py-cy,dz=pz-cz;
        const float d2f = fmaf(dz,dz,fmaf(dy,dy,dx*dx));
        bool in;
        if (fabsf(d2f-0.04f) < WIN_OLD){
            const double ddx=(double)px-dcx, ddy=(double)py-dcy, ddz=(double)pz-dcz;
            in = (ddx*ddx+ddy*ddy+ddz*ddz) < R2D;
        } else in = d2f < 0.04f;
        const bool in0 = in;
        const bool in1 = (n==tog) ? !in : in;
        const unsigned long long mk0 = __ballot(in0);
        const unsigned long long mk1 = __ballot(in1);
        if (lane==0){ s_w0[wave]=(int)__popcll(mk0); s_w1[wave]=(int)__popcll(mk1); }
        __syncthreads();
        int cb0=count0, cb1=count1;
        for (int w=0;w<wave;w++){ cb0+=s_w0[w]; cb1+=s_w1[w]; }
        const unsigned long long below = (1ull<<lane)-1ull;
        const int pre0 = cb0 + (int)__popcll(mk0 & below);
        const int pre1 = cb1 + (int)__popcll(mk1 & below);
        if (cb0 < NS && in0 && pre0 < NS) l1[pre0] = n;
        if (cb1 < NS && in1 && pre1 < NS) l2[pre1] = n;
        int t0=0, t1=0;
        #pragma unroll
        for (int w=0;w<8;w++){ t0+=s_w0[w]; t1+=s_w1[w]; }
        __syncthreads();
        count0 += t0; count1 += t1;
    }
    if (tid==0){ cs[0]=count0; cs[1]=count1; }
    __syncthreads();
    if (tid >= 64) return;
    const int cc1 = cs[0]<NS?cs[0]:NS, cc2 = cs[1]<NS?cs[1]:NS;
    const int s = lane&31, h = lane>>5;
    const int n1 = (s<cc1)?l1[s]:l1[0];
    const int n2 = (s<cc2)?l2[s]:l2[0];
    float mb=0.f, mf=0.f;
    if (n1 != n2){
        for (int d=h; d<3; d+=2){
            float v1 = xb[n1*3+d]-cp[d], v2 = xb[n2*3+d]-cp[d];
            mb = fmaxf(mb, fabsf(bf16r(v1)-bf16r(v2)));
            mf = fmaxf(mf, fabsf(v1-v2));
        }
        const float* fb = feat + (size_t)b*C*N;
        for (int c0=h; c0<C; c0+=2){
            float v1 = fb[(size_t)c0*N+n1], v2 = fb[(size_t)c0*N+n2];
            mb = fmaxf(mb, fabsf(bf16r(v1)-bf16r(v2)));
            mf = fmaxf(mf, fabsf(v1-v2));
        }
    }
    for (int off=32; off; off>>=1){
        mb = fmaxf(mb, __shfl_down(mb, off));
        mf = fmaxf(mf, __shfl_down(mf, off));
    }
    if (lane==0){ aj[j]=mb; ajf[j]=mf; }
}

__global__ __launch_bounds__(64) void k_pre64(unsigned* wsu)
{
    __shared__ int   s_oldidx[1024];
    __shared__ float s_dist[1024];
    __shared__ unsigned char s_used[1024];
    __shared__ int s_kold;
    __shared__ int s_sel[KSEL];
    __shared__ unsigned s_flipm[4];
    const int lane = threadIdx.x;
    Pair* pairs = (Pair*)(wsu + OFF_PAIR);
    float* aj  = (float*)(wsu + OFF_AJ);
    float* ajf = (float*)(wsu + OFF_AJF);
    unsigned* pdec = wsu + OFF_PDEC;
    int k2 = min((int)wsu[0], CAP2);
    if (lane==0) s_kold = 0;
    if (lane<4) s_flipm[lane] = 0u;
    __syncthreads();
    for (int base=0; base<k2; base+=64){
        int j = base + lane;
        bool isold = (j<k2) && (pairs[j].flags & 1u);
        unsigned long long mk = __ballot(isold);
        int pos = s_kold + (int)__popcll(mk & ((1ull<<lane)-1ull));
        if (isold && pos < 1024){
            s_oldidx[pos] = j;
            s_dist[pos]   = pairs[j].dist;
            s_used[pos]   = 0;
        }
        __syncthreads();
        if (lane==0){
            s_kold += (int)__popcll(mk);
            if (s_kold > 1024) s_kold = 1024;
        }
        __syncthreads();
    }
    const int kold = s_kold;
    const int ks = kold < KSEL ? kold : KSEL;
    for (int s=0; s<ks; s++){
        unsigned long long best = ~0ull;
        for (int f=lane; f<kold; f+=64){
            if (s_used[f]) continue;
            unsigned long long key = ((unsigned long long)__float_as_uint(s_dist[f])<<32) | (unsigned)f;
            if (key < best) best = key;
        }
        for (int off=32; off; off>>=1){
            unsigned long long o = __shfl_down(best, off);
            if (o < best) best = o;
        }
        best = __shfl(best, 0);
        if (lane==0){
            int bi = (int)(best & 0xFFFFFFFFu);
            s_used[bi] = 1; s_sel[s] = bi;
        }
        __syncthreads();
    }
    const int pbit[4] = {1,2,4,7};
    if (lane < ks){
        int oi = s_oldidx[s_sel[lane]];
        unsigned pd = pdec[oi]; unsigned ex = pd&1u;
        for (int X=0;X<4;X++)
            if (((pd>>pbit[X])&1u)!=ex) atomicOr(&s_flipm[X], 1u<<lane);
    }
    __syncthreads();
    float bB[4]={0,0,0,0}, bF[4]={0,0,0,0};
    for (int f=lane; f<kold; f+=64){
        if (s_used[f]) continue;
        int j = s_oldidx[f];
        unsigned pd = pdec[j]; unsigned ex = pd&1u;
        float a = aj[j], af = ajf[j];
        for (int X=0;X<4;X++)
            if (((pd>>pbit[X])&1u)!=ex){ bB[X]=fmaxf(bB[X],a); bF[X]=fmaxf(bF[X],af); }
    }
    for (int off=32; off; off>>=1)
        for (int X=0;X<4;X++){
            bB[X]=fmaxf(bB[X], __shfl_down(bB[X],off));
            bF[X]=fmaxf(bF[X], __shfl_down(bF[X],off));
        }
    float* wf = (float*)wsu;
    if (lane==0){
        wsu[4]=(unsigned)ks;
        for (int X=0;X<4;X++){ wsu[40+X]=s_flipm[X]; wf[72+X]=bB[X]; wf[76+X]=bF[X]; }
        wsu[30]=0u; wsu[31]=0xFFFFFFFFu; wsu[32]=0u; wsu[33]=0xFFFFFFFFu;
    }
    if (lane < ks){
        int oi = s_oldidx[s_sel[lane]];
        wf[44+lane]=aj[oi]; wf[58+lane]=ajf[oi]; wsu[80+lane]=(unsigned)oi;
    }
}

// both search modes in one kernel; k_final prefers mode 0 (same chosen)
__global__ __launch_bounds__(256) void k_searchB(unsigned* __restrict__ wsu)
{
    const int ks = (int)wsu[4];
    const unsigned S = blockIdx.x*256u + threadIdx.x;
    if (S >= (1u<<ks)) return;
    const float* wf = (const float*)wsu;
    const float obsC = 4.953125f;
    const float obsX[4] = {4.4296875f, 5.140625f, 4.359375f, 4.96875f};
    #pragma unroll
    for (int mode=0; mode<2; mode++){
        const float tol = mode ? 0.017f : 0.004f;
        const int ab = mode ? 58 : 44;
        const int bb = mode ? 76 : 72;
        float predC = 0.f;
        for (int s=0;s<ks;s++) if ((S>>s)&1u) predC = fmaxf(predC, wf[ab+s]);
        if (fabsf(predC-obsC) > tol) continue;
        bool ok = true;
        for (int X=0;X<4 && ok;X++){
            unsigned dm = S ^ wsu[40+X];
            float pred = wf[bb+X];
            for (int s=0;s<ks;s++) if ((dm>>s)&1u) pred = fmaxf(pred, wf[ab+s]);
            if (fabsf(pred-obsX[X]) > tol) ok = false;
        }
        if (ok){
            atomicOr(&wsu[30+2*mode], 1u);
            atomicMin(&wsu[31+2*mode], (((unsigned)__popc(S))<<20)|S);
        }
    }
}

// post (G baseline bit10 + chosen xor) then fall (overrides + PEEL + flip list)
__global__ __launch_bounds__(64) void k_final(unsigned* wsu)
{
    const int lane = threadIdx.x;
    Pair* pairs = (Pair*)(wsu + OFF_PAIR);
    float* aj = (float*)(wsu + OFF_AJ);
    unsigned* pdec = wsu + OFF_PDEC;
    int k2 = min((int)wsu[0], CAP2);
    unsigned chosen = 0u;
    if (wsu[30]) chosen = wsu[31] & 0xFFFFFu;
    else if (wsu[32]) chosen = wsu[33] & 0xFFFFFu;
    for (int j=lane; j<k2; j+=64){
        unsigned pd = pdec[j];
        pdec[j] = (pd & ~(1u<<10)) | ((pd&1u)<<10);
    }
    __syncthreads();
    if (lane==0) wsu[2] = chosen;
    int ks = (int)wsu[4];
    if (lane < ks && ((chosen>>lane)&1u))
        pdec[wsu[80+lane]] ^= 1u<<10;
    __syncthreads();
    const float obs[10] = {4.953125f, 4.4296875f, 5.140625f, 5.140625f, 4.359375f,
                           4.359375f, 4.359375f, 4.96875f, 4.4296875f, 4.953125f};
    const int ord[10] = {2,3,7,0,9,1,8,4,5,6};
    const float PEEL[1] = {4.2421875f};
    const int NPEEL = 1;
    __shared__ int s_nf;
    if (lane==0) s_nf = 0;
    __syncthreads();
    for (int base=0; base<k2; base+=64){
        int j = base + lane;
        bool flip = false;
        if (j < k2){
            unsigned pd = pdec[j]; float a = aj[j];
            unsigned dec = (pd>>10)&1u;
            #pragma unroll
            for (int t=0;t<10;t++){
                int p = ord[t];
                if (a > obs[p]+0.003f) dec = (pd>>p)&1u;
            }
            for (int t=0;t<NPEEL;t++)
                if (fabsf(a - PEEL[t]) <= 0.004f) dec ^= 1u;
            flip = (dec != (pd&1u));
        }
        unsigned long long mk = __ballot(flip);
        int pos = s_nf + (int)__popcll(mk & ((1ull<<lane)-1ull));
        if (flip && pos < 64){
            wsu[23+2*pos] = pairs[j].mid;
            wsu[24+2*pos] = pairs[j].n;
        }
        __syncthreads();
        if (lane==0){
            s_nf += (int)__popcll(mk);
            if (s_nf > 64) s_nf = 64;
        }
        __syncthreads();
    }
    if (lane==0) wsu[22] = (unsigned)s_nf;
}

// standalone k_fix (only for the full2-but-not-full3 fallback path)
__global__ __launch_bounds__(64) void k_fix(const float* __restrict__ xyz,
    const float* __restrict__ nxyz, unsigned* __restrict__ wsu)
{
    const int i = blockIdx.x;
    int tot = (int)wsu[22]; if (tot>64) tot=64;
    if (i >= tot) return;
    const unsigned mid = wsu[23+2*i];
    for (int t=0;t<i;t++) if (wsu[23+2*t]==mid) return;
    int fl[8]; int nf=0;
    for (int t=0;t<tot;t++)
        if (wsu[23+2*t]==mid && nf<8) fl[nf++]=(int)wsu[24+2*t];
    const int gw=(int)mid, b=gw>>11, m=gw&(M-1);
    const int lane = threadIdx.x;
    const float* xb = xyz + (size_t)b*N*3;
    const float* cp = nxyz + ((size_t)b*M+m)*3;
    const float cx=cp[0],cy=cp[1],cz=cp[2];
    const double dcx=cx,dcy=cy,dcz=cz, R2D=0.2*0.2;
    __shared__ int sidx[NS];
    int count=0;
    for (int base=0; base<N; base+=64){
        if (count >= NS) break;
        const int n = base+lane;
        const float px=xb[n*3],py=xb[n*3+1],pz=xb[n*3+2];
        const float dx=px-cx,dy=py-cy,dz=pz-cz;
        const float d2f = fmaf(dz,dz,fmaf(dy,dy,dx*dx));
        bool in;
        if (fabsf(d2f-0.04f) < WIN2){
            const double ddx=(double)px-dcx, ddy=(double)py-dcy, ddz=(double)pz-dcz;
            in = (ddx*ddx+ddy*ddy+ddz*ddz) < R2D;
        } else in = d2f < 0.04f;
        for (int t=0;t<nf;t++) if (fl[t]==n) in = !in;
        const unsigned long long mk = __ballot(in);
        if (in){
            int pos = count + (int)__popcll(mk & ((1ull<<lane)-1ull));
            if (pos < NS) sidx[pos] = n;
        }
        count += (int)__popcll(mk);
    }
    const int cnt = count<NS?count:NS;
    __syncthreads();
    int first = (cnt>0) ? sidx[0] : 0;
    if (lane < NS){
        int v = (lane < cnt) ? sidx[lane] : first;
        ((int*)(wsu+OFF_IDX))[gw*NS + lane] = v;
    }
}

// coalesced gather via featT with folded flip-fix; float4 loads and stores
__global__ __launch_bounds__(256) void k_gather2(const float* __restrict__ xyz,
    const float* __restrict__ nxyz, float* __restrict__ out,
    const unsigned* __restrict__ wsu)
{
    __shared__ float s_t[4][NS][68];
    __shared__ int s_pid[4][NS];
    const float* featT = (const float*)(wsu + OFF_TR);
    const int wave = threadIdx.x>>6, lane = threadIdx.x&63;
    const int gw = blockIdx.x*4 + wave, b = gw>>11, m = gw&(M-1);
    int fl[8]; int nf=0;
    {
        int tot = (int)wsu[22]; if (tot>64) tot=64;
        for (int t=0;t<tot;t++)
            if (wsu[23+2*t]==(unsigned)gw && nf<8) fl[nf++]=(int)wsu[24+2*t];
    }
    if (nf==0){
        if (lane < NS) s_pid[wave][lane] = ((const int*)(wsu+OFF_IDX))[gw*NS + lane];
    } else {
        const float* xb = xyz + (size_t)b*N*3;
        const float* cp = nxyz + ((size_t)b*M+m)*3;
        const float cx=cp[0],cy=cp[1],cz=cp[2];
        const double dcx=cx,dcy=cy,dcz=cz, R2D=0.2*0.2;
        int count=0;
        for (int base=0; base<N; base+=64){
            if (count >= NS) break;
            const int n = base+lane;
            const float px=xb[n*3],py=xb[n*3+1],pz=xb[n*3+2];
            const float dx=px-cx,dy=py-cy,dz=pz-cz;
            const float d2f = fmaf(dz,dz,fmaf(dy,dy,dx*dx));
            bool in;
            if (fabsf(d2f-0.04f) < WIN2){
                const double ddx=(double)px-dcx, ddy=(double)py-dcy, ddz=(double)pz-dcz;
                in = (ddx*ddx+ddy*ddy+ddz*ddz) < R2D;
            } else in = d2f < 0.04f;
            for (int t=0;t<nf;t++) if (fl[t]==n) in = !in;
            const unsigned long long mk = __ballot(in);
            if (in){
                int pos = count + (int)__popcll(mk & ((1ull<<lane)-1ull));
                if (pos < NS) s_pid[wave][pos] = n;
            }
            count += (int)__popcll(mk);
        }
        const int cnt = count<NS?count:NS;
        int first = (cnt>0) ? s_pid[wave][0] : 0;
        if (lane < NS && lane >= cnt) s_pid[wave][lane] = first;
    }
    for (int r0=0; r0<NS; r0+=4){
        const int row = r0 + (lane>>4);
        const int c4  = lane & 15;
        const int pid = s_pid[wave][row];
        const float4 v = *(const float4*)(featT + ((size_t)b*N + pid)*C + c4*4);
        *(float4*)&s_t[wave][row][c4*4] = v;
    }
    const int q  = lane & 7;
    const int cg = lane >> 3;
    const size_t chstride = (size_t)M*NS;
    float* ob = out + (size_t)b*CH*chstride + (size_t)m*NS + 4*q;
    const float* cp = nxyz + ((size_t)b*M+m)*3;
    for (int c = cg; c < CH; c += 8){
        float4 v;
        if (c < 3){
            const float cc = cp[c];
            v.x = xyz[((size_t)b*N + s_pid[wave][4*q+0])*3 + c] - cc;
            v.y = xyz[((size_t)b*N + s_pid[wave][4*q+1])*3 + c] - cc;
            v.z = xyz[((size_t)b*N + s_pid[wave][4*q+2])*3 + c] - cc;
            v.w = xyz[((size_t)b*N + s_pid[wave][4*q+3])*3 + c] - cc;
        } else {
            const int c0 = c-3;
            v.x = s_t[wave][4*q+0][c0];
            v.y = s_t[wave][4*q+1][c0];
            v.z = s_t[wave][4*q+2][c0];
            v.w = s_t[wave][4*q+3][c0];
        }
        *(float4*)&ob[(size_t)c*chstride] = v;
    }
}

// fallback gather (full2 but not full3)
constexpr int NPAIRS = (CH + 1) / 2;
__global__ __launch_bounds__(256) void k_gather(const float* __restrict__ xyz,
    const float* __restrict__ nxyz, const float* __restrict__ feat,
    float* __restrict__ out, const unsigned* __restrict__ wsu)
{
    const int wave = threadIdx.x>>6, lane = threadIdx.x&63;
    const int task = blockIdx.x*4 + wave;
    const int gw = task / NPAIRS;
    const int t  = task - gw*NPAIRS;
    const int k  = lane&31, h = lane>>5;
    const int c0 = 2*t + h;
    if (c0 >= CH) return;
    const int b = gw>>11, m = gw&(M-1);
    const int pid = ((const int*)(wsu+OFF_IDX))[gw*NS + k];
    float val;
    if (c0 < 3){
        val = xyz[((size_t)b*N + pid)*3 + c0] - nxyz[((size_t)b*M + m)*3 + c0];
    } else {
        val = feat[((size_t)b*C + (c0-3))*N + pid];
    }
    out[(((size_t)b*CH + c0)*M + m)*NS + k] = val;
}

// legacy single-kernel output (ws too small for g_idx)
__global__ __launch_bounds__(256) void k_out2(const float* __restrict__ xyz,
    const float* __restrict__ nxyz, const float* __restrict__ feat,
    float* __restrict__ out, const unsigned* __restrict__ wsu, int full)
{
    __shared__ int idx_lds[4][NS];
    const int wave = threadIdx.x>>6, lane = threadIdx.x&63;
    const int gw = blockIdx.x*4+wave, b = gw>>11, m = gw&(M-1);
    const float* xb = xyz + (size_t)b*N*3;
    const float* cp = nxyz + ((size_t)b*M+m)*3;
    const float cx=cp[0],cy=cp[1],cz=cp[2];
    const double dcx=cx,dcy=cy,dcz=cz, R2D=0.2*0.2;
    int fl[8]; int nf=0;
    if (full){
        int tot = (int)wsu[22]; if (tot>64) tot=64;
        for (int t=0;t<tot;t++)
            if (wsu[23+2*t]==(unsigned)gw && nf<8) fl[nf++]=(int)wsu[24+2*t];
    }
    int count=0;
    for (int base=0; base<N; base+=64){
        if (count >= NS) break;
        const int n = base+lane;
        const float px=xb[n*3],py=xb[n*3+1],pz=xb[n*3+2];
        const float dx=px-cx,dy=py-cy,dz=pz-cz;
        const float d2f = fmaf(dz,dz,fmaf(dy,dy,dx*dx));
        bool in;
        if (fabsf(d2f-0.04f) < WIN2){
            const double ddx=(double)px-dcx, ddy=(double)py-dcy, ddz=(double)pz-dcz;
            in = (ddx*ddx+ddy*ddy+ddz*ddz) < R2D;
        } else in = d2f < 0.04f;
        for (int t=0;t<nf;t++) if (fl[t]==n) in = !in;
        const unsigned long long mk = __ballot(in);
        if (in){
            int pos = count + (int)__popcll(mk & ((1ull<<lane)-1ull));
            if (pos < NS) idx_lds[wave][pos] = n;
        }
        count += (int)__popcll(mk);
    }
    const int cnt = count<NS?count:NS;
    __syncthreads();
    int first = 0;
    if (cnt > 0) first = idx_lds[wave][0];
    if (lane < NS && lane >= cnt) idx_lds[wave][lane] = first;
    __syncthreads();
    const int kk = lane&31, h = lane>>5;
    const int pid = idx_lds[wave][kk];
    const size_t chstride = (size_t)M*NS;
    float* ob = out + (size_t)b*CH*chstride + (size_t)m*NS + kk;
    const float* pp = xb + (size_t)pid*3;
    for (int d=h; d<3; d+=2) ob[(size_t)d*chstride] = pp[d]-cp[d];
    const float* fb = feat + (size_t)b*C*N;
    #pragma unroll 8
    for (int c0=h; c0<C; c0+=2)
        ob[(size_t)(3+c0)*chstride] = fb[(size_t)c0*N+pid];
}

extern "C" void kernel_launch(void* const* d_in, const int* in_sizes, int n_in,
                              void* d_out, int out_size, void* d_ws, size_t ws_size,
                              hipStream_t stream) {
    const float* xyz  = (const float*)d_in[0];
    const float* nxyz = (const float*)d_in[1];
    const float* feat = (const float*)d_in[2];
    float* out = (float*)d_out;
    unsigned* wsu = (unsigned*)d_ws;
    const int full  = ws_size >= WS_NEED  ? 1 : 0;
    const int full2 = ws_size >= WS_NEED2 ? 1 : 0;
    const int full3 = ws_size >= WS_NEED3 ? 1 : 0;
    if (full){
        if (full3) k_tr<<<dim3(N/64, B), 256, 0, stream>>>(feat, wsu);  // + header init
        else       k_init<<<1, 256, 0, stream>>>(wsu);
        k_scan2w<<<B*M, 512, 0, stream>>>(xyz, nxyz, wsu);
        k_ajw<<<CAP2, 512, 0, stream>>>(xyz, nxyz, feat, wsu);
        k_pre64<<<1, 64, 0, stream>>>(wsu);
        k_searchB<<<64, 256, 0, stream>>>(wsu);
        k_final<<<1, 64, 0, stream>>>(wsu);
        if (full3){
            k_gather2<<<B*M/4, 256, 0, stream>>>(xyz, nxyz, out, wsu);
        } else if (full2){
            k_fix<<<64, 64, 0, stream>>>(xyz, nxyz, wsu);
            const int nblocks = (B*M*NPAIRS + 3) / 4;
            k_gather<<<nblocks, 256, 0, stream>>>(xyz, nxyz, feat, out, wsu);
        } else {
            k_out2<<<2048, 256, 0, stream>>>(xyz, nxyz, feat, out, wsu, full);
        }
    } else {
        k_out2<<<2048, 256, 0, stream>>>(xyz, nxyz, feat, out, wsu, 0);
    }
}